// Round 2
// baseline (241.976 us; speedup 1.0000x reference)
//
#include <hip/hip_runtime.h>
#include <stdint.h>

#define K_DIM 4096
#define N_DIM 11008
#define NCOL  1376   // N/8

typedef __attribute__((ext_vector_type(4))) float  f32x4;
typedef __attribute__((ext_vector_type(8))) __bf16 bf16x8;

__device__ __forceinline__ void gload_lds16(const void* g, void* l) {
  __builtin_amdgcn_global_load_lds((const __attribute__((address_space(1))) void*)g,
                                   (__attribute__((address_space(3))) void*)l,
                                   16, 0, 0);
}

// ---------- prologue 1: x fp32 -> bf16 ----------
__global__ void __launch_bounds__(256) convert_x_kernel(const float* __restrict__ x,
                                                        __bf16* __restrict__ a) {
  size_t i = ((size_t)blockIdx.x * 256u + threadIdx.x) * 8u;
  f32x4 v0 = *(const f32x4*)(x + i);
  f32x4 v1 = *(const f32x4*)(x + i + 4);
  bf16x8 o;
  o[0] = (__bf16)v0[0]; o[1] = (__bf16)v0[1]; o[2] = (__bf16)v0[2]; o[3] = (__bf16)v0[3];
  o[4] = (__bf16)v1[0]; o[5] = (__bf16)v1[1]; o[6] = (__bf16)v1[2]; o[7] = (__bf16)v1[3];
  *(bf16x8*)(a + i) = o;
}

// ---------- prologue 2: AWQ dequant -> Wt bf16 [N][K] (transposed via LDS) ----------
__global__ void __launch_bounds__(256) dequant_kernel(const int* __restrict__ qw,
                                                      const int* __restrict__ qz,
                                                      const float* __restrict__ sc,
                                                      __bf16* __restrict__ wt) {
  constexpr int SH[8] = {0, 16, 4, 20, 8, 24, 12, 28};  // AWQ [0,4,1,5,2,6,3,7]*4
  __shared__ __bf16 tile[64][72];
  const int bid = blockIdx.x;
  const int tk = bid & 63;
  const int tn = bid >> 6;
  const int k0 = tk * 64;
  const int c0 = tn * 8;
  const int t = threadIdx.x;
#pragma unroll
  for (int r = 0; r < 2; ++r) {
    int idx = r * 256 + t;
    int kk = idx >> 3;
    int cc = idx & 7;
    int k = k0 + kk;
    int c = c0 + cc;
    uint32_t q  = (uint32_t)qw[(size_t)k * NCOL + c];
    int g = k >> 7;
    uint32_t zq = (uint32_t)qz[(size_t)g * NCOL + c];
    const float* s = sc + (size_t)g * N_DIM + (size_t)c * 8;
#pragma unroll
    for (int j = 0; j < 8; ++j) {
      int wv = (int)((q >> SH[j]) & 15u) - (int)((zq >> SH[j]) & 15u);
      tile[cc * 8 + j][kk] = (__bf16)((float)wv * s[j]);
    }
  }
  __syncthreads();
  const int n0 = tn * 64;
#pragma unroll
  for (int r = 0; r < 2; ++r) {
    int idx = r * 256 + t;
    int row = idx >> 3;
    int kc = idx & 7;
    bf16x8 v = *(const bf16x8*)&tile[row][kc * 8];
    *(bf16x8*)(wt + (size_t)(n0 + row) * K_DIM + k0 + kc * 8) = v;
  }
}

// ---------- main GEMM: 256x256 tile, BK=64, 8-phase counted-vmcnt schedule ----------
// 8 waves (2M x 4N), per-wave 128x64 output = 8x4 frags of 16x16x32 bf16 MFMA.
// LDS: 8 half-slots x 16KB (A0,A1,B0,B1 per K-tile, 2-tile rotation).
// Staging 6 halves (1.5 K-tiles) ahead, 1 half/phase, vmcnt(4) once per K-tile.
// Granule-XOR swizzle: physical granule p of row r holds source granule p^(r&7);
// linear gload_lds dest + inverse-swizzled global source + swizzled ds_read.
__global__ void __launch_bounds__(512, 2) wq_gemm256_kernel(
    const __bf16* __restrict__ A,    // [M][K] bf16
    const __bf16* __restrict__ Wt,   // [N][K] bf16
    const float* __restrict__ bias,
    float* __restrict__ out,
    const int Mblk)
{
  extern __shared__ char lds[];

  const int nwg = gridDim.x;
  int bid = blockIdx.x;
  if ((nwg & 7) == 0) {                 // XCD-aware swizzle (bijective: 344 % 8 == 0)
    const int cpx = nwg >> 3;
    bid = (bid & 7) * cpx + (bid >> 3);
  }
  const int bm = bid % Mblk;
  const int bn = bid / Mblk;
  const int m0 = bm * 256;
  const int n0 = bn * 256;

  const int t3 = threadIdx.x;
  const int lane = t3 & 63;
  const int w = t3 >> 6;     // 0..7
  const int wr = w >> 2;     // 0..1  (M half)
  const int wc = w & 3;      // 0..3  (N quarter)
  const int lrow = lane & 15;
  const int lk = lane >> 4;

  const __bf16* pA = A  + (size_t)m0 * K_DIM;
  const __bf16* pB = Wt + (size_t)n0 * K_DIM;
  const int rp0 = t3 >> 3;                       // row 0..63 (round 0)
  const int gl0 = (t3 & 7) ^ (rp0 & 7);          // inverse-swizzled source granule
  const size_t off0 = (size_t)rp0 * K_DIM + (size_t)gl0 * 8;
  const int woff = w * 1024;

#define STAGE(PBASE, ROWOFF, TILE, SLOT) do { \
    const __bf16* _s = (PBASE) + (size_t)(ROWOFF) * K_DIM + (size_t)(TILE) * 64 + off0; \
    gload_lds16(_s,              lds + (SLOT) * 16384 + woff); \
    gload_lds16(_s + 64 * K_DIM, lds + (SLOT) * 16384 + 8192 + woff); \
  } while (0)

  f32x4 acc[8][4];
#pragma unroll
  for (int i = 0; i < 8; ++i)
#pragma unroll
    for (int j = 0; j < 4; ++j) acc[i][j] = (f32x4){0.f, 0.f, 0.f, 0.f};

  // prologue: stage halves 0..5 (tile0 A0,A1,B0,B1; tile1 A0,A1)
  STAGE(pA, 0,   0, 0);
  STAGE(pA, 128, 0, 1);
  STAGE(pB, 0,   0, 2);
  STAGE(pB, 128, 0, 3);
  STAGE(pA, 0,   1, 4);
  STAGE(pA, 128, 1, 5);
  asm volatile("s_waitcnt vmcnt(4)" ::: "memory");  // halves 0..3 (tile 0) landed
  __builtin_amdgcn_s_barrier();

  const int g0 = (lk ^ (lrow & 7)) << 4;        // kk=0 granule byte offset
  const int g1 = ((4 + lk) ^ (lrow & 7)) << 4;  // kk=1
  const int arow = lrow * 128;
  const int boff = (wc & 1) * 8192 + lrow * 128;

#define MFMA_Q(AF, BF, MH, NH) do { \
    _Pragma("unroll") \
    for (int _m = 0; _m < 4; ++_m) { \
      _Pragma("unroll") \
      for (int _n = 0; _n < 2; ++_n) { \
        acc[(MH)+_m][(NH)+_n] = __builtin_amdgcn_mfma_f32_16x16x32_bf16(AF[_m][0], BF[_n][0], acc[(MH)+_m][(NH)+_n], 0, 0, 0); \
        acc[(MH)+_m][(NH)+_n] = __builtin_amdgcn_mfma_f32_16x16x32_bf16(AF[_m][1], BF[_n][1], acc[(MH)+_m][(NH)+_n], 0, 0, 0); \
      } } } while (0)

#define TILEBODY(T, SB, SBN) do { \
    const char* ab = lds + ((SB) + wr) * 16384 + arow; \
    const char* bb = lds + ((SB) + 2 + (wc >> 1)) * 16384 + boff; \
    bf16x8 alo[4][2], ahi[4][2], blo[2][2], bhi[2][2]; \
    /* ---- phase 1: Q(m0-3, n0-1) ---- */ \
    _Pragma("unroll") for (int m = 0; m < 4; ++m) { \
      alo[m][0] = *(const bf16x8*)(ab + g0 + m * 2048); \
      alo[m][1] = *(const bf16x8*)(ab + g1 + m * 2048); } \
    _Pragma("unroll") for (int n = 0; n < 2; ++n) { \
      blo[n][0] = *(const bf16x8*)(bb + g0 + n * 2048); \
      blo[n][1] = *(const bf16x8*)(bb + g1 + n * 2048); } \
    if ((T) < 63) STAGE(pB, 0, (T) + 1, (SBN) + 2); \
    __builtin_amdgcn_s_barrier(); \
    asm volatile("s_waitcnt lgkmcnt(0)"); \
    __builtin_amdgcn_s_setprio(1); \
    MFMA_Q(alo, blo, 0, 0); \
    __builtin_amdgcn_s_setprio(0); \
    __builtin_amdgcn_s_barrier(); \
    /* ---- phase 2: Q(m4-7, n0-1) ---- */ \
    _Pragma("unroll") for (int m = 0; m < 4; ++m) { \
      ahi[m][0] = *(const bf16x8*)(ab + g0 + 8192 + m * 2048); \
      ahi[m][1] = *(const bf16x8*)(ab + g1 + 8192 + m * 2048); } \
    if ((T) < 63) STAGE(pB, 128, (T) + 1, (SBN) + 3); \
    __builtin_amdgcn_s_barrier(); \
    asm volatile("s_waitcnt lgkmcnt(0)"); \
    __builtin_amdgcn_s_setprio(1); \
    MFMA_Q(ahi, blo, 4, 0); \
    __builtin_amdgcn_s_setprio(0); \
    __builtin_amdgcn_s_barrier(); \
    /* ---- phase 3: Q(m0-3, n2-3) ---- */ \
    _Pragma("unroll") for (int n = 0; n < 2; ++n) { \
      bhi[n][0] = *(const bf16x8*)(bb + g0 + (2 + n) * 2048); \
      bhi[n][1] = *(const bf16x8*)(bb + g1 + (2 + n) * 2048); } \
    if ((T) < 62) STAGE(pA, 0, (T) + 2, (SB) + 0); \
    __builtin_amdgcn_s_barrier(); \
    asm volatile("s_waitcnt lgkmcnt(0)"); \
    __builtin_amdgcn_s_setprio(1); \
    MFMA_Q(alo, bhi, 0, 2); \
    __builtin_amdgcn_s_setprio(0); \
    __builtin_amdgcn_s_barrier(); \
    /* ---- phase 4: Q(m4-7, n2-3) ---- */ \
    if ((T) < 62) STAGE(pA, 128, (T) + 2, (SB) + 1); \
    __builtin_amdgcn_s_barrier(); \
    __builtin_amdgcn_s_setprio(1); \
    MFMA_Q(ahi, bhi, 4, 2); \
    __builtin_amdgcn_s_setprio(0); \
    if ((T) < 62)      { asm volatile("s_waitcnt vmcnt(4)" ::: "memory"); } \
    else if ((T) == 62){ asm volatile("s_waitcnt vmcnt(0)" ::: "memory"); } \
    __builtin_amdgcn_s_barrier(); \
  } while (0)

  for (int t = 0; t < 64; t += 2) {
    TILEBODY(t,     0, 4);
    TILEBODY(t + 1, 4, 0);
  }

#undef TILEBODY
#undef MFMA_Q
#undef STAGE

  // epilogue: C/D layout col=lane&15, row=(lane>>4)*4+reg (m89-verified, R1-passed)
  const int orow = m0 + wr * 128 + lk * 4;
  const int ocol = n0 + wc * 64 + lrow;
#pragma unroll
  for (int n = 0; n < 4; ++n) {
    const int col = ocol + n * 16;
    const float bv = bias[col];
#pragma unroll
    for (int m = 0; m < 8; ++m) {
      float* po = out + (size_t)(orow + m * 16) * N_DIM + col;
      po[0]                 = acc[m][n][0] + bv;
      po[(size_t)N_DIM]     = acc[m][n][1] + bv;
      po[2 * (size_t)N_DIM] = acc[m][n][2] + bv;
      po[3 * (size_t)N_DIM] = acc[m][n][3] + bv;
    }
  }
}

extern "C" void kernel_launch(void* const* d_in, const int* in_sizes, int n_in,
                              void* d_out, int out_size, void* d_ws, size_t ws_size,
                              hipStream_t stream) {
  const float* x    = (const float*)d_in[0];
  const int* qw     = (const int*)d_in[1];
  const int* qz     = (const int*)d_in[2];
  const float* sc   = (const float*)d_in[3];
  const float* bias = (const float*)d_in[4];
  float* out = (float*)d_out;

  const int M = in_sizes[0] / K_DIM;        // 2048
  const int Mblk = M / 256;                 // 8
  const int grid = Mblk * (N_DIM / 256);    // 344 (divisible by 8)

  const size_t abytes = (size_t)M * K_DIM * 2;
  __bf16* Aw = (__bf16*)d_ws;
  __bf16* Wt = (__bf16*)((char*)d_ws + abytes);

  convert_x_kernel<<<(M * K_DIM) / 2048, 256, 0, stream>>>(x, Aw);
  dequant_kernel<<<(K_DIM / 64) * (N_DIM / 64), 256, 0, stream>>>(qw, qz, sc, Wt);

  hipFuncSetAttribute((const void*)wq_gemm256_kernel,
                      hipFuncAttributeMaxDynamicSharedMemorySize, 131072);
  wq_gemm256_kernel<<<grid, 512, 131072, stream>>>(Aw, Wt, bias, out, Mblk);
}

// Round 3
// 230.365 us; speedup vs baseline: 1.0504x; 1.0504x over previous
//
#include <hip/hip_runtime.h>
#include <stdint.h>

#define K_DIM 4096
#define N_DIM 11008
#define NCOL  1376   // N/8

typedef __attribute__((ext_vector_type(4))) float  f32x4;
typedef __attribute__((ext_vector_type(8))) __bf16 bf16x8;

__device__ __forceinline__ void gload_lds16(const void* g, void* l) {
  __builtin_amdgcn_global_load_lds((const __attribute__((address_space(1))) void*)g,
                                   (__attribute__((address_space(3))) void*)l,
                                   16, 0, 0);
}

// ---------- prologue 1: x fp32 -> bf16 ----------
__global__ void __launch_bounds__(256) convert_x_kernel(const float* __restrict__ x,
                                                        __bf16* __restrict__ a) {
  size_t i = ((size_t)blockIdx.x * 256u + threadIdx.x) * 8u;
  f32x4 v0 = *(const f32x4*)(x + i);
  f32x4 v1 = *(const f32x4*)(x + i + 4);
  bf16x8 o;
  o[0] = (__bf16)v0[0]; o[1] = (__bf16)v0[1]; o[2] = (__bf16)v0[2]; o[3] = (__bf16)v0[3];
  o[4] = (__bf16)v1[0]; o[5] = (__bf16)v1[1]; o[6] = (__bf16)v1[2]; o[7] = (__bf16)v1[3];
  *(bf16x8*)(a + i) = o;
}

// ---------- prologue 2: AWQ dequant -> Wt bf16 [N][K] (transposed via LDS) ----------
__global__ void __launch_bounds__(256) dequant_kernel(const int* __restrict__ qw,
                                                      const int* __restrict__ qz,
                                                      const float* __restrict__ sc,
                                                      __bf16* __restrict__ wt) {
  constexpr int SH[8] = {0, 16, 4, 20, 8, 24, 12, 28};  // AWQ [0,4,1,5,2,6,3,7]*4
  __shared__ __bf16 tile[64][72];
  const int bid = blockIdx.x;
  const int tk = bid & 63;
  const int tn = bid >> 6;
  const int k0 = tk * 64;
  const int c0 = tn * 8;
  const int t = threadIdx.x;
#pragma unroll
  for (int r = 0; r < 2; ++r) {
    int idx = r * 256 + t;
    int kk = idx >> 3;
    int cc = idx & 7;
    int k = k0 + kk;
    int c = c0 + cc;
    uint32_t q  = (uint32_t)qw[(size_t)k * NCOL + c];
    int g = k >> 7;
    uint32_t zq = (uint32_t)qz[(size_t)g * NCOL + c];
    const float* s = sc + (size_t)g * N_DIM + (size_t)c * 8;
#pragma unroll
    for (int j = 0; j < 8; ++j) {
      int wv = (int)((q >> SH[j]) & 15u) - (int)((zq >> SH[j]) & 15u);
      tile[cc * 8 + j][kk] = (__bf16)((float)wv * s[j]);
    }
  }
  __syncthreads();
  const int n0 = tn * 64;
#pragma unroll
  for (int r = 0; r < 2; ++r) {
    int idx = r * 256 + t;
    int row = idx >> 3;
    int kc = idx & 7;
    bf16x8 v = *(const bf16x8*)&tile[row][kc * 8];
    *(bf16x8*)(wt + (size_t)(n0 + row) * K_DIM + k0 + kc * 8) = v;
  }
}

// ---------- main GEMM: 256(M) x 128(N) tile, BK=64, 2-phase counted-vmcnt ----------
// 8 waves as 4M x 2N, per-wave 64x64 = 4x4 frags of 16x16x32 bf16 MFMA.
// LDS: 6 slots x 16KB = 96KB. Tile parity p: A(t) slots 3p+0 (rows 0-127),
// 3p+1 (rows 128-255); B(t) slot 3p+2 (rows 0-127).
// Per tile: ph1 {read A 8 + Blo 4; stage B(t+1); bar; lgkm0; 16 MFMA; bar}
//           ph2 {read Bhi 4; stage A0,A1(t+2); bar; lgkm0; 16 MFMA; vmcnt(4); bar}
// vmcnt(4) leaves A(t+2)'s 4 loads in flight; B(t+1) (issued earlier) proven landed.
// Granule-XOR swizzle: linear gload_lds dest + inverse-swizzled global source +
// swizzled ds_read (R1/R2-verified, bank conflicts == 0).
__global__ void __launch_bounds__(512, 2) wq_gemm_kernel(
    const __bf16* __restrict__ A,    // [M][K] bf16
    const __bf16* __restrict__ Wt,   // [N][K] bf16
    const float* __restrict__ bias,
    float* __restrict__ out,
    const int Mblk)
{
  extern __shared__ char lds[];

  const int nwg = gridDim.x;
  int bid = blockIdx.x;
  if ((nwg & 7) == 0) {                 // XCD-aware swizzle (688 % 8 == 0, bijective)
    const int cpx = nwg >> 3;
    bid = (bid & 7) * cpx + (bid >> 3);
  }
  const int bm = bid % Mblk;            // m-fastest: XCD chunk reuses B panels in L2
  const int bn = bid / Mblk;
  const int m0 = bm * 256;
  const int n0 = bn * 128;

  const int t3 = threadIdx.x;
  const int lane = t3 & 63;
  const int w = t3 >> 6;     // 0..7
  const int wr = w >> 1;     // 0..3  (M quarter)
  const int wc = w & 1;      // 0..1  (N half)
  const int lrow = lane & 15;
  const int lk = lane >> 4;

  const __bf16* pA = A  + (size_t)m0 * K_DIM;
  const __bf16* pB = Wt + (size_t)n0 * K_DIM;
  const int rp0 = t3 >> 3;                       // row 0..63 (first gload round)
  const int gl0 = (t3 & 7) ^ (rp0 & 7);          // inverse-swizzled source granule
  const size_t off0 = (size_t)rp0 * K_DIM + (size_t)gl0 * 8;
  const int woff = w * 1024;

#define STAGE(PBASE, ROWOFF, TILE, SLOT) do { \
    const __bf16* _s = (PBASE) + (size_t)(ROWOFF) * K_DIM + (size_t)(TILE) * 64 + off0; \
    gload_lds16(_s,              lds + (SLOT) * 16384 + woff); \
    gload_lds16(_s + 64 * K_DIM, lds + (SLOT) * 16384 + 8192 + woff); \
  } while (0)

  f32x4 acc[4][4];
#pragma unroll
  for (int i = 0; i < 4; ++i)
#pragma unroll
    for (int j = 0; j < 4; ++j) acc[i][j] = (f32x4){0.f, 0.f, 0.f, 0.f};

  // prologue: tile0 {A0->s0, A1->s1, B->s2}, tile1 {A0->s3, A1->s4}  (10 loads)
  STAGE(pA, 0,   0, 0);
  STAGE(pA, 128, 0, 1);
  STAGE(pB, 0,   0, 2);
  STAGE(pA, 0,   1, 3);
  STAGE(pA, 128, 1, 4);
  asm volatile("s_waitcnt vmcnt(4)" ::: "memory");  // tile0's 6 loads landed
  __builtin_amdgcn_s_barrier();

  const int g0 = (lk ^ (lrow & 7)) << 4;        // kk=0 granule byte offset
  const int g1 = ((4 + lk) ^ (lrow & 7)) << 4;  // kk=1
  const int aoff = (wr & 1) * 8192 + lrow * 128;  // within A slot (wr>>1 picks slot)
  const int boff = wc * 8192 + lrow * 128;        // within B slot

#define MFMA_P(NH) do { \
    _Pragma("unroll") \
    for (int _m = 0; _m < 4; ++_m) { \
      _Pragma("unroll") \
      for (int _n = 0; _n < 2; ++_n) { \
        acc[_m][(NH)+_n] = __builtin_amdgcn_mfma_f32_16x16x32_bf16(av[_m][0], bv[(NH)+_n][0], acc[_m][(NH)+_n], 0, 0, 0); \
        acc[_m][(NH)+_n] = __builtin_amdgcn_mfma_f32_16x16x32_bf16(av[_m][1], bv[(NH)+_n][1], acc[_m][(NH)+_n], 0, 0, 0); \
      } } } while (0)

#define TILEBODY(T, P) do { \
    const char* ab = lds + ((P) * 3 + (wr >> 1)) * 16384 + aoff; \
    const char* bb = lds + ((P) * 3 + 2) * 16384 + boff; \
    bf16x8 av[4][2], bv[4][2]; \
    /* ---- phase 1: all A, B lo ---- */ \
    _Pragma("unroll") for (int m = 0; m < 4; ++m) { \
      av[m][0] = *(const bf16x8*)(ab + g0 + m * 2048); \
      av[m][1] = *(const bf16x8*)(ab + g1 + m * 2048); } \
    _Pragma("unroll") for (int n = 0; n < 2; ++n) { \
      bv[n][0] = *(const bf16x8*)(bb + g0 + n * 2048); \
      bv[n][1] = *(const bf16x8*)(bb + g1 + n * 2048); } \
    if ((T) < 63) STAGE(pB, 0, (T) + 1, (1 - (P)) * 3 + 2); \
    __builtin_amdgcn_s_barrier(); \
    asm volatile("s_waitcnt lgkmcnt(0)"); \
    __builtin_amdgcn_s_setprio(1); \
    MFMA_P(0); \
    __builtin_amdgcn_s_setprio(0); \
    __builtin_amdgcn_s_barrier(); \
    /* ---- phase 2: all A (reused), B hi ---- */ \
    _Pragma("unroll") for (int n = 2; n < 4; ++n) { \
      bv[n][0] = *(const bf16x8*)(bb + g0 + n * 2048); \
      bv[n][1] = *(const bf16x8*)(bb + g1 + n * 2048); } \
    if ((T) < 62) { STAGE(pA, 0, (T) + 2, (P) * 3 + 0); \
                    STAGE(pA, 128, (T) + 2, (P) * 3 + 1); } \
    __builtin_amdgcn_s_barrier(); \
    asm volatile("s_waitcnt lgkmcnt(0)"); \
    __builtin_amdgcn_s_setprio(1); \
    MFMA_P(2); \
    __builtin_amdgcn_s_setprio(0); \
    if ((T) < 62)       { asm volatile("s_waitcnt vmcnt(4)" ::: "memory"); } \
    else if ((T) == 62) { asm volatile("s_waitcnt vmcnt(0)" ::: "memory"); } \
    __builtin_amdgcn_s_barrier(); \
  } while (0)

  for (int t = 0; t < 64; t += 2) {
    TILEBODY(t,     0);
    TILEBODY(t + 1, 1);
  }

#undef TILEBODY
#undef MFMA_P
#undef STAGE

  // epilogue: C/D layout col=lane&15, row=(lane>>4)*4+reg (m89-verified, R1/R2-passed)
  const int orow = m0 + wr * 64 + lk * 4;
  const int ocol = n0 + wc * 64 + lrow;
#pragma unroll
  for (int n = 0; n < 4; ++n) {
    const int col = ocol + n * 16;
    const float bv = bias[col];
#pragma unroll
    for (int m = 0; m < 4; ++m) {
      float* po = out + (size_t)(orow + m * 16) * N_DIM + col;
      po[0]                 = acc[m][n][0] + bv;
      po[(size_t)N_DIM]     = acc[m][n][1] + bv;
      po[2 * (size_t)N_DIM] = acc[m][n][2] + bv;
      po[3 * (size_t)N_DIM] = acc[m][n][3] + bv;
    }
  }
}

extern "C" void kernel_launch(void* const* d_in, const int* in_sizes, int n_in,
                              void* d_out, int out_size, void* d_ws, size_t ws_size,
                              hipStream_t stream) {
  const float* x    = (const float*)d_in[0];
  const int* qw     = (const int*)d_in[1];
  const int* qz     = (const int*)d_in[2];
  const float* sc   = (const float*)d_in[3];
  const float* bias = (const float*)d_in[4];
  float* out = (float*)d_out;

  const int M = in_sizes[0] / K_DIM;        // 2048
  const int Mblk = M / 256;                 // 8
  const int grid = Mblk * (N_DIM / 128);    // 8 * 86 = 688 (divisible by 8)

  const size_t abytes = (size_t)M * K_DIM * 2;
  __bf16* Aw = (__bf16*)d_ws;
  __bf16* Wt = (__bf16*)((char*)d_ws + abytes);

  convert_x_kernel<<<(M * K_DIM) / 2048, 256, 0, stream>>>(x, Aw);
  dequant_kernel<<<(K_DIM / 64) * (N_DIM / 64), 256, 0, stream>>>(qw, qz, sc, Wt);

  hipFuncSetAttribute((const void*)wq_gemm_kernel,
                      hipFuncAttributeMaxDynamicSharedMemorySize, 98304);
  wq_gemm_kernel<<<grid, 512, 98304, stream>>>(Aw, Wt, bias, out, Mblk);
}